// Round 4
// baseline (251.025 us; speedup 1.0000x reference)
//
#include <hip/hip_runtime.h>
#include <hip/hip_bf16.h>
#include <stdint.h>

// Problem constants (from reference): B=2048, C=200, F=32, H=256.
// All tensors fp32. M = B*C = 409600 rows of 32 features, contiguous in x.
#define M_ROWS 409600
#define B_CNT  2048
#define C_CNT  200

typedef __attribute__((ext_vector_type(8))) short bf16x8;   // 8 bf16 = 4 VGPRs
typedef __attribute__((ext_vector_type(4))) float f32x4;

// round-to-nearest-even f32 -> bf16 bits
__device__ __forceinline__ ushort f2bf(float f) {
    uint32_t u = __float_as_uint(f);
    u += 0x7fffu + ((u >> 16) & 1u);
    return (ushort)(u >> 16);
}

__device__ __forceinline__ f32x4 mfma16(bf16x8 a, bf16x8 b, f32x4 c) {
    return __builtin_amdgcn_mfma_f32_16x16x32_bf16(a, b, c, 0, 0, 0);
}

__device__ __forceinline__ bf16x8 pack8(float4 a, float4 b) {
    bf16x8 r;
    r[0] = (short)f2bf(a.x); r[1] = (short)f2bf(a.y);
    r[2] = (short)f2bf(a.z); r[3] = (short)f2bf(a.w);
    r[4] = (short)f2bf(b.x); r[5] = (short)f2bf(b.y);
    r[6] = (short)f2bf(b.z); r[7] = (short)f2bf(b.w);
    return r;
}

// ---------------------------------------------------------------------------
// xprep: one coalesced pass over x -> xb16 (bf16), Sc/Ic (compact exact fp32).
// Extra blocks transpose W1/W2 to bf16.
// ---------------------------------------------------------------------------
__global__ __launch_bounds__(256) void xprep_kernel(
    const float* __restrict__ x, const float* __restrict__ W1,
    const float* __restrict__ W2,
    ushort* __restrict__ xb16, float* __restrict__ Sc, float* __restrict__ Ic,
    ushort* __restrict__ W1t, ushort* __restrict__ W2t, int do_xb) {
    int blk = blockIdx.x, t = threadIdx.x;
    if (blk < B_CNT) {
        const float4* xr = (const float4*)(x + (size_t)blk * 6400);  // 1600 f4
        ushort4* xw = (ushort4*)(xb16 + (size_t)blk * 6400);
#pragma unroll
        for (int i = 0; i < 7; ++i) {
            int i4 = i * 256 + t;
            if (i4 < 1600) {
                float4 v = xr[i4];
                if (do_xb) {
                    ushort4 u;
                    u.x = f2bf(v.x); u.y = f2bf(v.y);
                    u.z = f2bf(v.z); u.w = f2bf(v.w);
                    xw[i4] = u;
                }
                if ((i4 & 7) == 0) {           // element i4*4 is feature 0 of c
                    int c = i4 >> 3;
                    Sc[blk * C_CNT + c] = v.x;
                    Ic[blk * C_CNT + c] = v.y;
                }
            }
        }
    } else if (blk < B_CNT + 256) {
        int n = blk - B_CNT;
        W2t[n * 256 + t] = f2bf(W2[t * 256 + n]);     // write coalesced
    } else {
        int idx = (blk - B_CNT - 256) * 256 + t;      // 0..8191
        int n = idx >> 5, k = idx & 31;
        W1t[idx] = f2bf(W1[k * 256 + n]);
    }
}

// ---------------------------------------------------------------------------
// inflow: sinflow = S@T, iinflow = I@T, exact fp32, T tiled through LDS.
// Block = 8 batch rows x 32 output cols; grid (7 col-tiles, 256 row-groups).
// ---------------------------------------------------------------------------
__global__ __launch_bounds__(256) void inflow_kernel(
    const float* __restrict__ Sc, const float* __restrict__ Ic,
    const float* __restrict__ T,
    float* __restrict__ sinW, float* __restrict__ iinW) {
    __shared__ float Ts[C_CNT * 33];   // T[cp][t0+j], row stride 33 (pad)
    __shared__ float SIs[8 * 2 * C_CNT]; // interleaved S,I per row

    const int t  = threadIdx.x;
    const int t0 = blockIdx.x * 32;
    const int b0 = blockIdx.y * 8;

    // stage T tile: coalesced global reads, 2-way (free) LDS writes
    for (int i = t; i < 6400; i += 256) {
        int cp = i >> 5, j = i & 31, col = t0 + j;
        Ts[cp * 33 + j] = (col < C_CNT) ? T[cp * C_CNT + col] : 0.f;
    }
    // stage S/I rows (compact, coalesced)
    for (int i = t; i < 1600; i += 256) {
        int bi = i / C_CNT, cp = i % C_CNT;
        float2 si; si.x = Sc[(b0 + bi) * C_CNT + cp];
        si.y = Ic[(b0 + bi) * C_CNT + cp];
        *(float2*)&SIs[bi * 2 * C_CNT + 2 * cp] = si;
    }
    __syncthreads();

    const int ti = t & 31, bi = t >> 5, col = t0 + ti;
    float as = 0.f, ai = 0.f;
    const float* sip = &SIs[bi * 2 * C_CNT];
#pragma unroll 4
    for (int cp = 0; cp < C_CNT; ++cp) {
        float tv = Ts[cp * 33 + ti];
        float2 si = *(const float2*)&sip[2 * cp];
        as = fmaf(si.x, tv, as);
        ai = fmaf(si.y, tv, ai);
    }
    if (col < C_CNT) {
        sinW[(b0 + bi) * C_CNT + col] = as;
        iinW[(b0 + bi) * C_CNT + col] = ai;
    }
}

// ---------------------------------------------------------------------------
// Fused MLP kernel. One block = 64 rows, 4 waves (wave w owns n in [64w,64w+64)).
// GEMM2 K-loop is register double-buffered: LDS B-frags prefetched 1 ahead
// (before MFMAs), global W2t A-frags prefetched ~2 ahead (kc0/kc1 issued
// before the barrier). Biases/W3 are direct float4 loads (no LDS, no barrier).
// MFMA 16x16x32 frags: A[m=lane&15][k=q*8+j], B[k=q*8+j][n=lane&15],
// C/D col=lane&15, row=q*4+reg.
// ---------------------------------------------------------------------------
template <bool XB>
__global__ __launch_bounds__(256, 3) void mlp_kernel(
    const float* __restrict__ x,
    const ushort* __restrict__ xb16,
    const float* __restrict__ T,
    const float* __restrict__ b1,
    const float* __restrict__ b2,
    const float* __restrict__ W3,
    const float* __restrict__ b3,
    const ushort* __restrict__ W1t,   // [256][32]  bf16, n1-major
    const ushort* __restrict__ W2t,   // [256][256] bf16, n2-major
    const float* __restrict__ Sc, const float* __restrict__ Ic,
    const float* __restrict__ sinW, const float* __restrict__ iinW,
    float* __restrict__ out) {
    constexpr int RS = 264;  // h1 row stride: 256+8, rows 16B-aligned
    __shared__ ushort h1s[64 * RS];          // 33792 B
    __shared__ float lamb_part[4][64];

    const int tid  = threadIdx.x;
    const int w    = tid >> 6;
    const int lane = tid & 63;
    const int L    = lane & 15;
    const int q    = lane >> 4;
    const int m0   = blockIdx.x * 64;

    // ---- GEMM1 (K=32): A from bf16 W1t, B from bf16 xb16 (or fp32 x) ----
    bf16x8 aw[4], bx[4];
#pragma unroll
    for (int i = 0; i < 4; ++i) {
        int n1 = 64 * w + i * 16 + L;
        aw[i] = *(const bf16x8*)(W1t + n1 * 32 + q * 8);
        if (XB) {
            bx[i] = *(const bf16x8*)(xb16 + (size_t)(m0 + i * 16 + L) * 32 + q * 8);
        } else {
            const float4* xr = (const float4*)(x + (size_t)(m0 + i * 16 + L) * 32 + q * 8);
            bx[i] = pack8(xr[0], xr[1]);
        }
    }
    // direct bias loads (broadcast within 16-lane groups, L2-hot)
    float4 b1v[4];
#pragma unroll
    for (int i1 = 0; i1 < 4; ++i1)
        b1v[i1] = *(const float4*)(b1 + 64 * w + i1 * 16 + q * 4);

    f32x4 acc1[4][4];
#pragma unroll
    for (int i1 = 0; i1 < 4; ++i1)
#pragma unroll
        for (int im = 0; im < 4; ++im)
            acc1[i1][im] = mfma16(aw[i1], bx[im], (f32x4){0.f, 0.f, 0.f, 0.f});

    // ---- early prefetch of W2t fragments for kc=0,1 (independent of LDS) ----
    bf16x8 a2[2][4], bh[2][4];
#pragma unroll
    for (int i2 = 0; i2 < 4; ++i2) {
        int n2 = 64 * w + i2 * 16 + L;
        a2[0][i2] = *(const bf16x8*)(W2t + n2 * 256 + 0 * 32 + q * 8);
        a2[1][i2] = *(const bf16x8*)(W2t + n2 * 256 + 1 * 32 + q * 8);
    }

    // fp32 bias + relu, one bf16 rounding; 4 consecutive n1 -> ds_write_b64
#pragma unroll
    for (int i1 = 0; i1 < 4; ++i1) {
        int n1b = 64 * w + i1 * 16 + q * 4;
#pragma unroll
        for (int im = 0; im < 4; ++im) {
            int m = im * 16 + L;
            float v0 = fmaxf(acc1[i1][im][0] + b1v[i1].x, 0.f);
            float v1 = fmaxf(acc1[i1][im][1] + b1v[i1].y, 0.f);
            float v2 = fmaxf(acc1[i1][im][2] + b1v[i1].z, 0.f);
            float v3 = fmaxf(acc1[i1][im][3] + b1v[i1].w, 0.f);
            uint2 pk;
            pk.x = (uint32_t)f2bf(v0) | ((uint32_t)f2bf(v1) << 16);
            pk.y = (uint32_t)f2bf(v2) | ((uint32_t)f2bf(v3) << 16);
            *reinterpret_cast<uint2*>(&h1s[m * RS + n1b]) = pk;
        }
    }
    __syncthreads();   // the ONLY barrier before GEMM2

    // ---- GEMM2 (K=256, 8 k-chunks), register double-buffered ----
    f32x4 acc2[4][4];
#pragma unroll
    for (int i2 = 0; i2 < 4; ++i2)
#pragma unroll
        for (int im = 0; im < 4; ++im) acc2[i2][im] = (f32x4){0.f, 0.f, 0.f, 0.f};

    // LDS B-frags for kc=0
#pragma unroll
    for (int im = 0; im < 4; ++im)
        bh[0][im] = *(const bf16x8*)(&h1s[(im * 16 + L) * RS + q * 8]);

#pragma unroll
    for (int kc = 0; kc < 8; ++kc) {
        const int cur = kc & 1, nxt = cur ^ 1;
        // prefetch next LDS B-frags BEFORE this chunk's MFMAs
        if (kc < 7) {
#pragma unroll
            for (int im = 0; im < 4; ++im)
                bh[nxt][im] = *(const bf16x8*)(
                    &h1s[(im * 16 + L) * RS + (kc + 1) * 32 + q * 8]);
        }
#pragma unroll
        for (int i2 = 0; i2 < 4; ++i2)
#pragma unroll
            for (int im = 0; im < 4; ++im)
                acc2[i2][im] = mfma16(a2[cur][i2], bh[cur][im], acc2[i2][im]);
        // prefetch W2t A-frags for kc+2 into the slot just freed
        if (kc < 6) {
#pragma unroll
            for (int i2 = 0; i2 < 4; ++i2) {
                int n2 = 64 * w + i2 * 16 + L;
                a2[cur][i2] = *(const bf16x8*)(W2t + n2 * 256 + (kc + 2) * 32 + q * 8);
            }
        }
    }

    // ---- GEMM3: lamb[m] = sum_n2 relu(h2 + b2) * W3 (fp32, exact) ----
    float4 b2v[4], w3v[4];
#pragma unroll
    for (int i2 = 0; i2 < 4; ++i2) {
        b2v[i2] = *(const float4*)(b2 + 64 * w + i2 * 16 + q * 4);
        w3v[i2] = *(const float4*)(W3 + 64 * w + i2 * 16 + q * 4);
    }
    float part[4] = {0.f, 0.f, 0.f, 0.f};
#pragma unroll
    for (int i2 = 0; i2 < 4; ++i2) {
#pragma unroll
        for (int im = 0; im < 4; ++im) {
            part[im] = fmaf(fmaxf(acc2[i2][im][0] + b2v[i2].x, 0.f), w3v[i2].x, part[im]);
            part[im] = fmaf(fmaxf(acc2[i2][im][1] + b2v[i2].y, 0.f), w3v[i2].y, part[im]);
            part[im] = fmaf(fmaxf(acc2[i2][im][2] + b2v[i2].z, 0.f), w3v[i2].z, part[im]);
            part[im] = fmaf(fmaxf(acc2[i2][im][3] + b2v[i2].w, 0.f), w3v[i2].w, part[im]);
        }
    }
#pragma unroll
    for (int im = 0; im < 4; ++im) {
        float p = part[im];
        p += __shfl_xor(p, 16);
        p += __shfl_xor(p, 32);
        if (q == 0) lamb_part[w][im * 16 + L] = p;
    }
    __syncthreads();

    // ---- epilogue: one thread per row, all reads compact & coalesced ----
    if (tid < 64) {
        int gm = m0 + tid;
        float lam = lamb_part[0][tid] + lamb_part[1][tid] +
                    lamb_part[2][tid] + lamb_part[3][tid] + b3[0];
        float S = Sc[gm], I = Ic[gm];
        int c = gm % C_CNT;
        float of = 1.0f - T[c * C_CNT + c];
        float sv = sinW[gm], iv = iinW[gm];
        float dS = -lam * S + sv - of * S;
        float dI =  lam * S + iv - of * I;
        float2 o; o.x = S + dS; o.y = I + dI;
        ((float2*)out)[gm] = o;   // coalesced 8B store -> out[2gm], out[2gm+1]
    }
}

// ---------------------------------------------------------------------------
extern "C" void kernel_launch(void* const* d_in, const int* in_sizes, int n_in,
                              void* d_out, int out_size, void* d_ws, size_t ws_size,
                              hipStream_t stream) {
    const float* x  = (const float*)d_in[0];
    const float* T  = (const float*)d_in[1];
    const float* W1 = (const float*)d_in[2];
    const float* b1 = (const float*)d_in[3];
    const float* W2 = (const float*)d_in[4];
    const float* b2 = (const float*)d_in[5];
    const float* W3 = (const float*)d_in[6];
    const float* b3 = (const float*)d_in[7];

    // ws layout: [xb16 (opt, 26.2 MB)] Sc Ic sin iin (4x1.64 MB) W1t W2t (144KB)
    const size_t xb_bytes = (size_t)M_ROWS * 32 * 2;
    const size_t f32_arr  = (size_t)M_ROWS * 4;
    const size_t small    = 4 * f32_arr + 8192 * 2 + 65536 * 2;
    const int    do_xb    = (ws_size >= xb_bytes + small) ? 1 : 0;

    char* ws = (char*)d_ws;
    ushort* xb16 = (ushort*)ws;
    char* base = ws + (do_xb ? xb_bytes : 0);
    float*  Sc   = (float*)(base);
    float*  Ic   = (float*)(base + f32_arr);
    float*  sinW = (float*)(base + 2 * f32_arr);
    float*  iinW = (float*)(base + 3 * f32_arr);
    ushort* W1t  = (ushort*)(base + 4 * f32_arr);
    ushort* W2t  = (ushort*)(base + 4 * f32_arr + 8192 * 2);

    hipLaunchKernelGGL(xprep_kernel, dim3(B_CNT + 256 + 32), dim3(256), 0, stream,
                       x, W1, W2, xb16, Sc, Ic, W1t, W2t, do_xb);
    hipLaunchKernelGGL(inflow_kernel, dim3(7, 256), dim3(256), 0, stream,
                       Sc, Ic, T, sinW, iinW);
    if (do_xb) {
        hipLaunchKernelGGL((mlp_kernel<true>), dim3(M_ROWS / 64), dim3(256), 0, stream,
                           x, xb16, T, b1, b2, W3, b3, W1t, W2t, Sc, Ic, sinW, iinW,
                           (float*)d_out);
    } else {
        hipLaunchKernelGGL((mlp_kernel<false>), dim3(M_ROWS / 64), dim3(256), 0, stream,
                           x, xb16, T, b1, b2, W3, b3, W1t, W2t, Sc, Ic, sinW, iinW,
                           (float*)d_out);
    }
}